// Round 8
// baseline (192.201 us; speedup 1.0000x reference)
//
#include <hip/hip_runtime.h>

typedef unsigned short u16;
typedef unsigned int   u32;
typedef __bf16 bf16x8 __attribute__((ext_vector_type(8)));
typedef float  f32x4  __attribute__((ext_vector_type(4)));
typedef u16    u16x8  __attribute__((ext_vector_type(8)));
typedef u16    u16x4  __attribute__((ext_vector_type(4)));

__device__ __forceinline__ float b2f(u16 h) {
  return __builtin_bit_cast(float, ((u32)h) << 16);
}
__device__ __forceinline__ u16 f2b(float f) {
  u32 u = __builtin_bit_cast(u32, f);
  u32 r = u + 0x7FFFu + ((u >> 16) & 1u);
  return (u16)(r >> 16);
}

#define GLD_AS1(p) ((const __attribute__((address_space(1))) void*)(p))
#define LDS_AS3(p) ((__attribute__((address_space(3))) void*)(p))

// ---------------------------------------------------------------------------
// GEMM1 + fused softmax + IN-EPILOGUE context partials.
// Grid 1536, 1-D XCD swizzle: tn = id>>7 (0..11), tm = 0..127.
//   tn 0..3  : q cols [tn*128, +128)  -> softmax -> qb row-major
//   tn 4..11 : head j = tn-4; B-tile rows = Wt[512+64j..+64) U Wt[1024+64j..+64)
//              i.e. the block holds k'_j (cols 0..63) and v_j (cols 64..127)
//              for 128 n-rows. Epilogue: softmax(k), two-phase LDS transpose
//              (T = 128 cols x 64 n, stride 72 -> 18.4 KB, unioned w/ staging),
//              MFMA ctx partial (d x e, K=128), store fp32 ctxp[s][bh].
// ---------------------------------------------------------------------------
__global__ void gemm_qkv_kernel(const u16* __restrict__ A, const u16* __restrict__ Bt,
                                u16* __restrict__ qb, float* __restrict__ ctxp) {
  const int K = 512;
  __shared__ u16 smem[2 * 64 * 72];  // staging (16 KB) U transpose scratch T
  u16* As = smem;
  u16* Bs = smem + 128 * 32;
  const int id = blockIdx.x;
  const int tn = id >> 7;
  const int tm = (id & 7) * 16 + ((id >> 3) & 15);
  const int tileM = tm * 128;
  const int t = threadIdx.x;
  const int lane = t & 63;
  const int wave = t >> 6;
  const int mbase = (wave >> 1) * 64;
  const int nbase = (wave & 1) * 64;
  const int fm = lane & 15;
  const int kg = lane >> 4;
  const bool is_q = (tn < 4);
  const int j = tn - 4;

  f32x4 acc[4][4];
#pragma unroll
  for (int i = 0; i < 4; ++i)
#pragma unroll
    for (int jj = 0; jj < 4; ++jj) acc[i][jj] = (f32x4){0.f, 0.f, 0.f, 0.f};

  for (int k0 = 0; k0 < K; k0 += 32) {
#pragma unroll
    for (int p = 0; p < 2; ++p) {
      int c = p * 256 + t;
      int r = c >> 2;
      int g = (c & 3) ^ ((r >> 1) & 3);
      const u16* ga = A + (size_t)(tileM + r) * K + (k0 + g * 8);
      __builtin_amdgcn_global_load_lds(GLD_AS1(ga), LDS_AS3(As + c * 8), 16, 0, 0);
      int brow = is_q ? (tn * 128 + r) : (512 + j * 64 + r + (r >> 6) * 448);
      const u16* gb = Bt + (size_t)brow * K + (k0 + g * 8);
      __builtin_amdgcn_global_load_lds(GLD_AS1(gb), LDS_AS3(Bs + c * 8), 16, 0, 0);
    }
    __syncthreads();

    bf16x8 af[4], bfr[4];
#pragma unroll
    for (int mi = 0; mi < 4; ++mi) {
      int m = mbase + mi * 16 + fm;
      int sg = kg ^ ((m >> 1) & 3);
      af[mi] = *(const bf16x8*)(As + m * 32 + sg * 8);
    }
#pragma unroll
    for (int ni = 0; ni < 4; ++ni) {
      int n = nbase + ni * 16 + fm;
      int sg = kg ^ ((n >> 1) & 3);
      bfr[ni] = *(const bf16x8*)(Bs + n * 32 + sg * 8);
    }
#pragma unroll
    for (int mi = 0; mi < 4; ++mi)
#pragma unroll
      for (int ni = 0; ni < 4; ++ni)
        acc[mi][ni] = __builtin_amdgcn_mfma_f32_16x16x32_bf16(af[mi], bfr[ni],
                                                              acc[mi][ni], 0, 0, 0);
    __syncthreads();   // drains staging; As/Bs dead after last iter
  }

  const int rq = lane >> 4;

  // softmax: q blocks -> all waves; kv blocks -> k-waves only (wave&1==0)
  float inv[4][4];
  const bool do_sm = is_q || ((wave & 1) == 0);
  if (do_sm) {
#pragma unroll
    for (int mi = 0; mi < 4; ++mi)
#pragma unroll
      for (int ni = 0; ni < 4; ++ni)
#pragma unroll
        for (int reg = 0; reg < 4; ++reg)
          acc[mi][ni][reg] = __expf(acc[mi][ni][reg]);
#pragma unroll
    for (int mi = 0; mi < 4; ++mi)
#pragma unroll
      for (int reg = 0; reg < 4; ++reg) {
        float s = acc[mi][0][reg] + acc[mi][1][reg] + acc[mi][2][reg] + acc[mi][3][reg];
        s += __shfl_xor(s, 1);
        s += __shfl_xor(s, 2);
        s += __shfl_xor(s, 4);
        s += __shfl_xor(s, 8);
        inv[mi][reg] = 1.f / s;
      }
  } else {
#pragma unroll
    for (int mi = 0; mi < 4; ++mi)
#pragma unroll
      for (int reg = 0; reg < 4; ++reg) inv[mi][reg] = 1.f;
  }

  if (is_q) {
#pragma unroll
    for (int mi = 0; mi < 4; ++mi)
#pragma unroll
      for (int ni = 0; ni < 4; ++ni)
#pragma unroll
        for (int reg = 0; reg < 4; ++reg) {
          int gr = tileM + mbase + mi * 16 + rq * 4 + reg;
          int gc = tn * 128 + nbase + ni * 16 + fm;
          qb[(size_t)gr * 512 + gc] = f2b(acc[mi][ni][reg] * inv[mi][reg]);
        }
    return;
  }

  // kv epilogue: two n-half phases; T[c][n] c=0..127 (0-63 k'd, 64-127 v e),
  // n local 0..63, stride 72.
  u16* T = smem;
  f32x4 cacc[4];
#pragma unroll
  for (int i = 0; i < 4; ++i) cacc[i] = (f32x4){0.f, 0.f, 0.f, 0.f};

#pragma unroll
  for (int ph = 0; ph < 2; ++ph) {
    if ((wave >> 1) == ph) {
#pragma unroll
      for (int mi = 0; mi < 4; ++mi)
#pragma unroll
        for (int ni = 0; ni < 4; ++ni) {
          u16x4 o;
#pragma unroll
          for (int reg = 0; reg < 4; ++reg)
            o[reg] = f2b(acc[mi][ni][reg] * inv[mi][reg]);
          int c = nbase + ni * 16 + fm;
          *(u16x4*)(T + c * 72 + mi * 16 + rq * 4) = o;
        }
    }
    __syncthreads();
    // ctx += k'^T v over this n-half (K=64). A rows: T[0..63] (d), B rows:
    // T[64..127] (e); both n-contiguous. Wave covers d-strip wave*16.
#pragma unroll
    for (int kk = 0; kk < 2; ++kk) {
      bf16x8 afc = *(const bf16x8*)(T + (wave * 16 + fm) * 72 + kk * 32 + kg * 8);
#pragma unroll
      for (int et = 0; et < 4; ++et) {
        bf16x8 bfc = *(const bf16x8*)(T + (64 + et * 16 + fm) * 72 + kk * 32 + kg * 8);
        cacc[et] = __builtin_amdgcn_mfma_f32_16x16x32_bf16(afc, bfc, cacc[et], 0, 0, 0);
      }
    }
    __syncthreads();
  }

  // store partial: ctxp[s=tm&31][bh][d][e]
  const int b = tm >> 5;
  const int s = tm & 31;
  float* cp = ctxp + ((size_t)s * 32 + b * 8 + j) * 4096;
#pragma unroll
  for (int et = 0; et < 4; ++et)
#pragma unroll
    for (int reg = 0; reg < 4; ++reg)
      cp[(wave * 16 + rq * 4 + reg) * 64 + et * 16 + fm] = cacc[et][reg];
}

// ---------------------------------------------------------------------------
// prep_all: [0,4096) cast x; [4096,4288) Wt tiles; [4288,4352) Wot tiles.
// ---------------------------------------------------------------------------
__global__ void prep_all_kernel(const float* __restrict__ x, const float* __restrict__ Wq,
                                const float* __restrict__ Wk, const float* __restrict__ Wv,
                                const float* __restrict__ Wo, u16* __restrict__ xb,
                                u16* __restrict__ Wt, u16* __restrict__ Wot) {
  __shared__ u16 tr[64 * 72];
  const int id = blockIdx.x;
  const int t = threadIdx.x;

  if (id < 4096) {
    int i = (id * 256 + t) * 8;
    float4 a = *(const float4*)(x + i);
    float4 b = *(const float4*)(x + i + 4);
    u16x8 o;
    o[0] = f2b(a.x); o[1] = f2b(a.y); o[2] = f2b(a.z); o[3] = f2b(a.w);
    o[4] = f2b(b.x); o[5] = f2b(b.y); o[6] = f2b(b.z); o[7] = f2b(b.w);
    *(u16x8*)(xb + i) = o;
    return;
  }
  const float* W;
  u16* dst;
  int n0, k0;
  if (id < 4288) {
    int tile = id - 4096;
    n0 = (tile >> 3) * 64;
    k0 = (tile & 7) * 64;
    W = (n0 < 512) ? Wq : ((n0 < 1024) ? Wk : Wv);
    dst = Wt;
  } else {
    int tile = id - 4288;
    n0 = (tile >> 3) * 64;
    k0 = (tile & 7) * 64;
    W = Wo;
    dst = Wot;
  }
  int cin = (n0 & 511);
  int c = t & 63;
  int r0 = t >> 6;
#pragma unroll
  for (int i = 0; i < 16; ++i) {
    int r = r0 * 16 + i;
    tr[c * 72 + r] = f2b(W[(size_t)(k0 + r) * 512 + cin + c]);
  }
  __syncthreads();
#pragma unroll
  for (int jj = 0; jj < 2; ++jj) {
    int idx = jj * 256 + t;
    int row = idx >> 3;
    int seg = idx & 7;
    u16x8 val = *(const u16x8*)(tr + row * 72 + seg * 8);
    *(u16x8*)(dst + (size_t)(n0 + row) * 512 + k0 + seg * 8) = val;
  }
}

// ---------------------------------------------------------------------------
// ctxm: per (b,h): reduce 32 ctxp partials -> ctx_h (64d x 64e, bf16, LDS),
// then Mt[b][c][h*64+d] = sum_e Wot[c][h*64+e] * ctx_h[d][e]  (MFMA K=64).
// ---------------------------------------------------------------------------
__global__ void ctxm_kernel(const float* __restrict__ ctxp, const u16* __restrict__ Wot,
                            u16* __restrict__ Mt) {
  __shared__ u16 ctxd[64 * 72];
  const int bh = blockIdx.x;
  const int b = bh >> 3, h = bh & 7;
  const int t = threadIdx.x;
  const int lane = t & 63;
  const int wave = t >> 6;
  const int fm = lane & 15;
  const int kg = lane >> 4;
  const int rq = lane >> 4;

#pragma unroll
  for (int it = 0; it < 4; ++it) {
    int idx = it * 1024 + t * 4;
    f32x4 s = (f32x4){0.f, 0.f, 0.f, 0.f};
#pragma unroll
    for (int p = 0; p < 32; ++p)
      s += *(const f32x4*)(ctxp + ((size_t)p * 32 + bh) * 4096 + idx);
    u16x4 o;
#pragma unroll
    for (int jj = 0; jj < 4; ++jj) o[jj] = f2b(s[jj]);
    int d = idx >> 6, e = idx & 63;
    *(u16x4*)(ctxd + d * 72 + e) = o;
  }
  __syncthreads();

  f32x4 acc[8][4];
#pragma unroll
  for (int i = 0; i < 8; ++i)
#pragma unroll
    for (int jj = 0; jj < 4; ++jj) acc[i][jj] = (f32x4){0.f, 0.f, 0.f, 0.f};

#pragma unroll
  for (int ks = 0; ks < 2; ++ks) {
    bf16x8 bfr[4];
#pragma unroll
    for (int dt = 0; dt < 4; ++dt)
      bfr[dt] = *(const bf16x8*)(ctxd + (dt * 16 + fm) * 72 + ks * 32 + kg * 8);
#pragma unroll
    for (int mi = 0; mi < 8; ++mi) {
      int c = wave * 128 + mi * 16 + fm;
      bf16x8 af = *(const bf16x8*)(Wot + (size_t)c * 512 + h * 64 + ks * 32 + kg * 8);
#pragma unroll
      for (int dt = 0; dt < 4; ++dt)
        acc[mi][dt] = __builtin_amdgcn_mfma_f32_16x16x32_bf16(af, bfr[dt],
                                                              acc[mi][dt], 0, 0, 0);
    }
  }

  u16* mb = Mt + (size_t)b * 512 * 512;
#pragma unroll
  for (int mi = 0; mi < 8; ++mi)
#pragma unroll
    for (int dt = 0; dt < 4; ++dt)
#pragma unroll
      for (int reg = 0; reg < 4; ++reg) {
        int c = wave * 128 + mi * 16 + rq * 4 + reg;
        mb[(size_t)c * 512 + h * 64 + dt * 16 + fm] = f2b(acc[mi][dt][reg]);
      }
}

// ---------------------------------------------------------------------------
// Final GEMM: out[b] = q'[b] @ Mt[b]^T + bo  (batched over b via tileM).
// ---------------------------------------------------------------------------
__global__ void gemm_out_kernel(const u16* __restrict__ A, const u16* __restrict__ Mt,
                                float* __restrict__ Cout, const float* __restrict__ bias) {
  const int K = 512, N = 512;
  __shared__ u16 As[128 * 32];
  __shared__ u16 Bs[128 * 32];
  const int id = blockIdx.x;
  const int tn = id >> 7;
  const int tm = (id & 7) * 16 + ((id >> 3) & 15);
  const int tileN = tn * 128;
  const int tileM = tm * 128;
  const u16* Bt = Mt + (size_t)(tm >> 5) * 512 * 512;
  const int t = threadIdx.x;
  const int lane = t & 63;
  const int wave = t >> 6;
  const int mbase = (wave >> 1) * 64;
  const int nbase = (wave & 1) * 64;
  const int fm = lane & 15;
  const int kg = lane >> 4;

  f32x4 acc[4][4];
#pragma unroll
  for (int i = 0; i < 4; ++i)
#pragma unroll
    for (int jj = 0; jj < 4; ++jj) acc[i][jj] = (f32x4){0.f, 0.f, 0.f, 0.f};

  for (int k0 = 0; k0 < K; k0 += 32) {
#pragma unroll
    for (int p = 0; p < 2; ++p) {
      int c = p * 256 + t;
      int r = c >> 2;
      int g = (c & 3) ^ ((r >> 1) & 3);
      const u16* ga = A + (size_t)(tileM + r) * K + (k0 + g * 8);
      __builtin_amdgcn_global_load_lds(GLD_AS1(ga), LDS_AS3(As + c * 8), 16, 0, 0);
      const u16* gb = Bt + (size_t)(tileN + r) * K + (k0 + g * 8);
      __builtin_amdgcn_global_load_lds(GLD_AS1(gb), LDS_AS3(Bs + c * 8), 16, 0, 0);
    }
    __syncthreads();

    bf16x8 af[4], bfr[4];
#pragma unroll
    for (int mi = 0; mi < 4; ++mi) {
      int m = mbase + mi * 16 + fm;
      int sg = kg ^ ((m >> 1) & 3);
      af[mi] = *(const bf16x8*)(As + m * 32 + sg * 8);
    }
#pragma unroll
    for (int ni = 0; ni < 4; ++ni) {
      int n = nbase + ni * 16 + fm;
      int sg = kg ^ ((n >> 1) & 3);
      bfr[ni] = *(const bf16x8*)(Bs + n * 32 + sg * 8);
    }
#pragma unroll
    for (int mi = 0; mi < 4; ++mi)
#pragma unroll
      for (int ni = 0; ni < 4; ++ni)
        acc[mi][ni] = __builtin_amdgcn_mfma_f32_16x16x32_bf16(af[mi], bfr[ni],
                                                              acc[mi][ni], 0, 0, 0);
    __syncthreads();
  }

  const int rq = lane >> 4;
#pragma unroll
  for (int mi = 0; mi < 4; ++mi)
#pragma unroll
    for (int ni = 0; ni < 4; ++ni)
#pragma unroll
      for (int reg = 0; reg < 4; ++reg) {
        int gr = tileM + mbase + mi * 16 + rq * 4 + reg;
        int gc = tileN + nbase + ni * 16 + fm;
        Cout[(size_t)gr * N + gc] = acc[mi][ni][reg] + bias[gc];
      }
}

// ---------------------------------------------------------------------------
extern "C" void kernel_launch(void* const* d_in, const int* in_sizes, int n_in,
                              void* d_out, int out_size, void* d_ws, size_t ws_size,
                              hipStream_t stream) {
  const float* x  = (const float*)d_in[0];
  const float* Wq = (const float*)d_in[1];
  const float* Wk = (const float*)d_in[2];
  const float* Wv = (const float*)d_in[3];
  const float* Wo = (const float*)d_in[4];
  const float* bo = (const float*)d_in[5];

  char* w = (char*)d_ws;
  u16* xb   = (u16*)w;    w += (size_t)16384 * 512 * 2;     // 16.8 MB
  u16* Wt   = (u16*)w;    w += (size_t)1536 * 512 * 2;      // 1.6 MB
  u16* Wot  = (u16*)w;    w += (size_t)512 * 512 * 2;       // 0.5 MB
  u16* qbuf = (u16*)w;    w += (size_t)16384 * 512 * 2;     // 16.8 MB
  float* ctxp = (float*)w; w += (size_t)32 * 32 * 4096 * 4; // 16.8 MB
  u16* Mt   = (u16*)w;    w += (size_t)4 * 512 * 512 * 2;   // 2.1 MB

  prep_all_kernel<<<4352, 256, 0, stream>>>(x, Wq, Wk, Wv, Wo, xb, Wt, Wot);
  gemm_qkv_kernel<<<1536, 256, 0, stream>>>(xb, Wt, qbuf, ctxp);
  ctxm_kernel<<<32, 256, 0, stream>>>(ctxp, Wot, Mt);
  gemm_out_kernel<<<512, 256, 0, stream>>>(qbuf, Mt, (float*)d_out, bo);
}

// Round 9
// 155.638 us; speedup vs baseline: 1.2349x; 1.2349x over previous
//
#include <hip/hip_runtime.h>

typedef unsigned short u16;
typedef unsigned int   u32;
typedef __bf16 bf16x8 __attribute__((ext_vector_type(8)));
typedef float  f32x4  __attribute__((ext_vector_type(4)));
typedef u16    u16x8  __attribute__((ext_vector_type(8)));
typedef u16    u16x4  __attribute__((ext_vector_type(4)));

__device__ __forceinline__ float b2f(u16 h) {
  return __builtin_bit_cast(float, ((u32)h) << 16);
}
__device__ __forceinline__ u16 f2b(float f) {
  u32 u = __builtin_bit_cast(u32, f);
  u32 r = u + 0x7FFFu + ((u >> 16) & 1u);
  return (u16)(r >> 16);
}

#define GLD_AS1(p) ((const __attribute__((address_space(1))) void*)(p))
#define LDS_AS3(p) ((__attribute__((address_space(3))) void*)(p))

// ---------------------------------------------------------------------------
// GEMM1 + fused softmax + IN-EPILOGUE context partials. (unchanged from R8)
// ---------------------------------------------------------------------------
__global__ void gemm_qkv_kernel(const u16* __restrict__ A, const u16* __restrict__ Bt,
                                u16* __restrict__ qb, float* __restrict__ ctxp) {
  const int K = 512;
  __shared__ u16 smem[2 * 64 * 72];  // staging (16 KB) U transpose scratch T
  u16* As = smem;
  u16* Bs = smem + 128 * 32;
  const int id = blockIdx.x;
  const int tn = id >> 7;
  const int tm = (id & 7) * 16 + ((id >> 3) & 15);
  const int tileM = tm * 128;
  const int t = threadIdx.x;
  const int lane = t & 63;
  const int wave = t >> 6;
  const int mbase = (wave >> 1) * 64;
  const int nbase = (wave & 1) * 64;
  const int fm = lane & 15;
  const int kg = lane >> 4;
  const bool is_q = (tn < 4);
  const int j = tn - 4;

  f32x4 acc[4][4];
#pragma unroll
  for (int i = 0; i < 4; ++i)
#pragma unroll
    for (int jj = 0; jj < 4; ++jj) acc[i][jj] = (f32x4){0.f, 0.f, 0.f, 0.f};

  for (int k0 = 0; k0 < K; k0 += 32) {
#pragma unroll
    for (int p = 0; p < 2; ++p) {
      int c = p * 256 + t;
      int r = c >> 2;
      int g = (c & 3) ^ ((r >> 1) & 3);
      const u16* ga = A + (size_t)(tileM + r) * K + (k0 + g * 8);
      __builtin_amdgcn_global_load_lds(GLD_AS1(ga), LDS_AS3(As + c * 8), 16, 0, 0);
      int brow = is_q ? (tn * 128 + r) : (512 + j * 64 + r + (r >> 6) * 448);
      const u16* gb = Bt + (size_t)brow * K + (k0 + g * 8);
      __builtin_amdgcn_global_load_lds(GLD_AS1(gb), LDS_AS3(Bs + c * 8), 16, 0, 0);
    }
    __syncthreads();

    bf16x8 af[4], bfr[4];
#pragma unroll
    for (int mi = 0; mi < 4; ++mi) {
      int m = mbase + mi * 16 + fm;
      int sg = kg ^ ((m >> 1) & 3);
      af[mi] = *(const bf16x8*)(As + m * 32 + sg * 8);
    }
#pragma unroll
    for (int ni = 0; ni < 4; ++ni) {
      int n = nbase + ni * 16 + fm;
      int sg = kg ^ ((n >> 1) & 3);
      bfr[ni] = *(const bf16x8*)(Bs + n * 32 + sg * 8);
    }
#pragma unroll
    for (int mi = 0; mi < 4; ++mi)
#pragma unroll
      for (int ni = 0; ni < 4; ++ni)
        acc[mi][ni] = __builtin_amdgcn_mfma_f32_16x16x32_bf16(af[mi], bfr[ni],
                                                              acc[mi][ni], 0, 0, 0);
    __syncthreads();
  }

  const int rq = lane >> 4;

  float inv[4][4];
  const bool do_sm = is_q || ((wave & 1) == 0);
  if (do_sm) {
#pragma unroll
    for (int mi = 0; mi < 4; ++mi)
#pragma unroll
      for (int ni = 0; ni < 4; ++ni)
#pragma unroll
        for (int reg = 0; reg < 4; ++reg)
          acc[mi][ni][reg] = __expf(acc[mi][ni][reg]);
#pragma unroll
    for (int mi = 0; mi < 4; ++mi)
#pragma unroll
      for (int reg = 0; reg < 4; ++reg) {
        float s = acc[mi][0][reg] + acc[mi][1][reg] + acc[mi][2][reg] + acc[mi][3][reg];
        s += __shfl_xor(s, 1);
        s += __shfl_xor(s, 2);
        s += __shfl_xor(s, 4);
        s += __shfl_xor(s, 8);
        inv[mi][reg] = 1.f / s;
      }
  } else {
#pragma unroll
    for (int mi = 0; mi < 4; ++mi)
#pragma unroll
      for (int reg = 0; reg < 4; ++reg) inv[mi][reg] = 1.f;
  }

  if (is_q) {
#pragma unroll
    for (int mi = 0; mi < 4; ++mi)
#pragma unroll
      for (int ni = 0; ni < 4; ++ni)
#pragma unroll
        for (int reg = 0; reg < 4; ++reg) {
          int gr = tileM + mbase + mi * 16 + rq * 4 + reg;
          int gc = tn * 128 + nbase + ni * 16 + fm;
          qb[(size_t)gr * 512 + gc] = f2b(acc[mi][ni][reg] * inv[mi][reg]);
        }
    return;
  }

  u16* T = smem;
  f32x4 cacc[4];
#pragma unroll
  for (int i = 0; i < 4; ++i) cacc[i] = (f32x4){0.f, 0.f, 0.f, 0.f};

#pragma unroll
  for (int ph = 0; ph < 2; ++ph) {
    if ((wave >> 1) == ph) {
#pragma unroll
      for (int mi = 0; mi < 4; ++mi)
#pragma unroll
        for (int ni = 0; ni < 4; ++ni) {
          u16x4 o;
#pragma unroll
          for (int reg = 0; reg < 4; ++reg)
            o[reg] = f2b(acc[mi][ni][reg] * inv[mi][reg]);
          int c = nbase + ni * 16 + fm;
          *(u16x4*)(T + c * 72 + mi * 16 + rq * 4) = o;
        }
    }
    __syncthreads();
#pragma unroll
    for (int kk = 0; kk < 2; ++kk) {
      bf16x8 afc = *(const bf16x8*)(T + (wave * 16 + fm) * 72 + kk * 32 + kg * 8);
#pragma unroll
      for (int et = 0; et < 4; ++et) {
        bf16x8 bfc = *(const bf16x8*)(T + (64 + et * 16 + fm) * 72 + kk * 32 + kg * 8);
        cacc[et] = __builtin_amdgcn_mfma_f32_16x16x32_bf16(afc, bfc, cacc[et], 0, 0, 0);
      }
    }
    __syncthreads();
  }

  const int b = tm >> 5;
  const int s = tm & 31;
  float* cp = ctxp + ((size_t)s * 32 + b * 8 + j) * 4096;
#pragma unroll
  for (int et = 0; et < 4; ++et)
#pragma unroll
    for (int reg = 0; reg < 4; ++reg)
      cp[(wave * 16 + rq * 4 + reg) * 64 + et * 16 + fm] = cacc[et][reg];
}

// ---------------------------------------------------------------------------
// prep_all: [0,4096) cast x; [4096,4288) Wt tiles; [4288,4352) Wot tiles.
// ---------------------------------------------------------------------------
__global__ void prep_all_kernel(const float* __restrict__ x, const float* __restrict__ Wq,
                                const float* __restrict__ Wk, const float* __restrict__ Wv,
                                const float* __restrict__ Wo, u16* __restrict__ xb,
                                u16* __restrict__ Wt, u16* __restrict__ Wot) {
  __shared__ u16 tr[64 * 72];
  const int id = blockIdx.x;
  const int t = threadIdx.x;

  if (id < 4096) {
    int i = (id * 256 + t) * 8;
    float4 a = *(const float4*)(x + i);
    float4 b = *(const float4*)(x + i + 4);
    u16x8 o;
    o[0] = f2b(a.x); o[1] = f2b(a.y); o[2] = f2b(a.z); o[3] = f2b(a.w);
    o[4] = f2b(b.x); o[5] = f2b(b.y); o[6] = f2b(b.z); o[7] = f2b(b.w);
    *(u16x8*)(xb + i) = o;
    return;
  }
  const float* W;
  u16* dst;
  int n0, k0;
  if (id < 4288) {
    int tile = id - 4096;
    n0 = (tile >> 3) * 64;
    k0 = (tile & 7) * 64;
    W = (n0 < 512) ? Wq : ((n0 < 1024) ? Wk : Wv);
    dst = Wt;
  } else {
    int tile = id - 4288;
    n0 = (tile >> 3) * 64;
    k0 = (tile & 7) * 64;
    W = Wo;
    dst = Wot;
  }
  int cin = (n0 & 511);
  int c = t & 63;
  int r0 = t >> 6;
#pragma unroll
  for (int i = 0; i < 16; ++i) {
    int r = r0 * 16 + i;
    tr[c * 72 + r] = f2b(W[(size_t)(k0 + r) * 512 + cin + c]);
  }
  __syncthreads();
#pragma unroll
  for (int jj = 0; jj < 2; ++jj) {
    int idx = jj * 256 + t;
    int row = idx >> 3;
    int seg = idx & 7;
    u16x8 val = *(const u16x8*)(tr + row * 72 + seg * 8);
    *(u16x8*)(dst + (size_t)(n0 + row) * 512 + k0 + seg * 8) = val;
  }
}

// ---------------------------------------------------------------------------
// ctx_reduce: WIDE reduction. Grid 128: (bh = id>>2, chunk = id&3).
// ctxb[bh][idx] (bf16) = sum_s ctxp[s][bh][idx], idx in chunk*1024 + t*4.
// 16.8 MB read spread over 128 blocks, fully coalesced.
// ---------------------------------------------------------------------------
__global__ void ctx_reduce_kernel(const float* __restrict__ ctxp, u16* __restrict__ ctxb) {
  const int id = blockIdx.x;
  const int bh = id >> 2;
  const int chunk = id & 3;
  const int t = threadIdx.x;
  const int idx = chunk * 1024 + t * 4;
  f32x4 s = (f32x4){0.f, 0.f, 0.f, 0.f};
#pragma unroll
  for (int p = 0; p < 32; ++p)
    s += *(const f32x4*)(ctxp + ((size_t)p * 32 + bh) * 4096 + idx);
  u16x4 o;
#pragma unroll
  for (int jj = 0; jj < 4; ++jj) o[jj] = f2b(s[jj]);
  *(u16x4*)(ctxb + (size_t)bh * 4096 + idx) = o;
}

// ---------------------------------------------------------------------------
// ctxm_mfma: Grid 128: (bh = id>>2, cq = id&3). Stage ctxb_h (8 KB) in LDS,
// then Mt[b][c][h*64+d] = sum_e Wot[c][h*64+e] * ctx_h[d][e]  (MFMA K=64).
// Wave w owns c-range [cq*128 + w*32, +32).
// ---------------------------------------------------------------------------
__global__ void ctxm_kernel(const u16* __restrict__ ctxb, const u16* __restrict__ Wot,
                            u16* __restrict__ Mt) {
  __shared__ u16 ctxd[64 * 72];
  const int id = blockIdx.x;
  const int bh = id >> 2;
  const int cq = id & 3;
  const int b = bh >> 3, h = bh & 7;
  const int t = threadIdx.x;
  const int lane = t & 63;
  const int wave = t >> 6;
  const int fm = lane & 15;
  const int kg = lane >> 4;
  const int rq = lane >> 4;

  {
    int base = t * 16;                 // 256 thr x 16 elems = 4096
    int d = base >> 6, e = base & 63;
    u16x8 v0 = *(const u16x8*)(ctxb + (size_t)bh * 4096 + base);
    u16x8 v1 = *(const u16x8*)(ctxb + (size_t)bh * 4096 + base + 8);
    *(u16x8*)(ctxd + d * 72 + e) = v0;
    *(u16x8*)(ctxd + d * 72 + e + 8) = v1;
  }
  __syncthreads();

  f32x4 acc[2][4];
#pragma unroll
  for (int i = 0; i < 2; ++i)
#pragma unroll
    for (int jj = 0; jj < 4; ++jj) acc[i][jj] = (f32x4){0.f, 0.f, 0.f, 0.f};

#pragma unroll
  for (int ks = 0; ks < 2; ++ks) {
    bf16x8 bfr[4];
#pragma unroll
    for (int dt = 0; dt < 4; ++dt)
      bfr[dt] = *(const bf16x8*)(ctxd + (dt * 16 + fm) * 72 + ks * 32 + kg * 8);
#pragma unroll
    for (int mi = 0; mi < 2; ++mi) {
      int c = cq * 128 + wave * 32 + mi * 16 + fm;
      bf16x8 af = *(const bf16x8*)(Wot + (size_t)c * 512 + h * 64 + ks * 32 + kg * 8);
#pragma unroll
      for (int dt = 0; dt < 4; ++dt)
        acc[mi][dt] = __builtin_amdgcn_mfma_f32_16x16x32_bf16(af, bfr[dt],
                                                              acc[mi][dt], 0, 0, 0);
    }
  }

  u16* mb = Mt + (size_t)b * 512 * 512;
#pragma unroll
  for (int mi = 0; mi < 2; ++mi)
#pragma unroll
    for (int dt = 0; dt < 4; ++dt)
#pragma unroll
      for (int reg = 0; reg < 4; ++reg) {
        int c = cq * 128 + wave * 32 + mi * 16 + rq * 4 + reg;
        mb[(size_t)c * 512 + h * 64 + dt * 16 + fm] = f2b(acc[mi][dt][reg]);
      }
}

// ---------------------------------------------------------------------------
// Final GEMM: out[b] = q'[b] @ Mt[b]^T + bo  (batched over b via tileM).
// ---------------------------------------------------------------------------
__global__ void gemm_out_kernel(const u16* __restrict__ A, const u16* __restrict__ Mt,
                                float* __restrict__ Cout, const float* __restrict__ bias) {
  const int K = 512, N = 512;
  __shared__ u16 As[128 * 32];
  __shared__ u16 Bs[128 * 32];
  const int id = blockIdx.x;
  const int tn = id >> 7;
  const int tm = (id & 7) * 16 + ((id >> 3) & 15);
  const int tileN = tn * 128;
  const int tileM = tm * 128;
  const u16* Bt = Mt + (size_t)(tm >> 5) * 512 * 512;
  const int t = threadIdx.x;
  const int lane = t & 63;
  const int wave = t >> 6;
  const int mbase = (wave >> 1) * 64;
  const int nbase = (wave & 1) * 64;
  const int fm = lane & 15;
  const int kg = lane >> 4;

  f32x4 acc[4][4];
#pragma unroll
  for (int i = 0; i < 4; ++i)
#pragma unroll
    for (int jj = 0; jj < 4; ++jj) acc[i][jj] = (f32x4){0.f, 0.f, 0.f, 0.f};

  for (int k0 = 0; k0 < K; k0 += 32) {
#pragma unroll
    for (int p = 0; p < 2; ++p) {
      int c = p * 256 + t;
      int r = c >> 2;
      int g = (c & 3) ^ ((r >> 1) & 3);
      const u16* ga = A + (size_t)(tileM + r) * K + (k0 + g * 8);
      __builtin_amdgcn_global_load_lds(GLD_AS1(ga), LDS_AS3(As + c * 8), 16, 0, 0);
      const u16* gb = Bt + (size_t)(tileN + r) * K + (k0 + g * 8);
      __builtin_amdgcn_global_load_lds(GLD_AS1(gb), LDS_AS3(Bs + c * 8), 16, 0, 0);
    }
    __syncthreads();

    bf16x8 af[4], bfr[4];
#pragma unroll
    for (int mi = 0; mi < 4; ++mi) {
      int m = mbase + mi * 16 + fm;
      int sg = kg ^ ((m >> 1) & 3);
      af[mi] = *(const bf16x8*)(As + m * 32 + sg * 8);
    }
#pragma unroll
    for (int ni = 0; ni < 4; ++ni) {
      int n = nbase + ni * 16 + fm;
      int sg = kg ^ ((n >> 1) & 3);
      bfr[ni] = *(const bf16x8*)(Bs + n * 32 + sg * 8);
    }
#pragma unroll
    for (int mi = 0; mi < 4; ++mi)
#pragma unroll
      for (int ni = 0; ni < 4; ++ni)
        acc[mi][ni] = __builtin_amdgcn_mfma_f32_16x16x32_bf16(af[mi], bfr[ni],
                                                              acc[mi][ni], 0, 0, 0);
    __syncthreads();
  }

  const int rq = lane >> 4;
#pragma unroll
  for (int mi = 0; mi < 4; ++mi)
#pragma unroll
    for (int ni = 0; ni < 4; ++ni)
#pragma unroll
      for (int reg = 0; reg < 4; ++reg) {
        int gr = tileM + mbase + mi * 16 + rq * 4 + reg;
        int gc = tileN + nbase + ni * 16 + fm;
        Cout[(size_t)gr * N + gc] = acc[mi][ni][reg] + bias[gc];
      }
}

// ---------------------------------------------------------------------------
extern "C" void kernel_launch(void* const* d_in, const int* in_sizes, int n_in,
                              void* d_out, int out_size, void* d_ws, size_t ws_size,
                              hipStream_t stream) {
  const float* x  = (const float*)d_in[0];
  const float* Wq = (const float*)d_in[1];
  const float* Wk = (const float*)d_in[2];
  const float* Wv = (const float*)d_in[3];
  const float* Wo = (const float*)d_in[4];
  const float* bo = (const float*)d_in[5];

  char* w = (char*)d_ws;
  u16* xb   = (u16*)w;    w += (size_t)16384 * 512 * 2;     // 16.8 MB
  u16* Wt   = (u16*)w;    w += (size_t)1536 * 512 * 2;      // 1.6 MB
  u16* Wot  = (u16*)w;    w += (size_t)512 * 512 * 2;       // 0.5 MB
  u16* qbuf = (u16*)w;    w += (size_t)16384 * 512 * 2;     // 16.8 MB
  float* ctxp = (float*)w; w += (size_t)32 * 32 * 4096 * 4; // 16.8 MB
  u16* ctxb = (u16*)w;    w += (size_t)32 * 4096 * 2;       // 0.26 MB
  u16* Mt   = (u16*)w;    w += (size_t)4 * 512 * 512 * 2;   // 2.1 MB

  prep_all_kernel<<<4352, 256, 0, stream>>>(x, Wq, Wk, Wv, Wo, xb, Wt, Wot);
  gemm_qkv_kernel<<<1536, 256, 0, stream>>>(xb, Wt, qbuf, ctxp);
  ctx_reduce_kernel<<<128, 256, 0, stream>>>(ctxp, ctxb);
  ctxm_kernel<<<128, 256, 0, stream>>>(ctxb, Wot, Mt);
  gemm_out_kernel<<<512, 256, 0, stream>>>(qbuf, Mt, (float*)d_out, bo);
}